// Round 10
// baseline (241.540 us; speedup 1.0000x reference)
//
#include <hip/hip_runtime.h>
#include <hip/hip_bf16.h>

typedef unsigned short u16;
typedef unsigned int u32;
typedef __attribute__((ext_vector_type(8))) short bf16x8;
typedef __attribute__((ext_vector_type(4))) float f32x4;

#define LOG2E 1.44269504088896340736f
#define QSCALE (0.125f * LOG2E)
#define DEFER_THR 8.0f

// ---------- helpers ----------

__device__ inline u16 f2bf(float f) {            // RNE
  union { float f; u32 u; } v; v.f = f;
  u32 r = v.u + 0x7fffu + ((v.u >> 16) & 1u);
  return (u16)(r >> 16);
}

__device__ inline void gload_lds16(const void* g, void* l) {
  __builtin_amdgcn_global_load_lds(
      (const __attribute__((address_space(1))) u32*)g,
      (__attribute__((address_space(3))) u32*)l, 16, 0, 0);
}

// DPP move within 16-lane rows (row_ror:N = 0x120+N)
template<int CTRL>
__device__ inline float dppmov(float x) {
  int i = __builtin_bit_cast(int, x);
  int r = __builtin_amdgcn_update_dpp(i, i, CTRL, 0xf, 0xf, false);
  return __builtin_bit_cast(float, r);
}
__device__ inline float rowmax16(float v) {
  v = fmaxf(v, dppmov<0x128>(v));
  v = fmaxf(v, dppmov<0x124>(v));
  v = fmaxf(v, dppmov<0x122>(v));
  v = fmaxf(v, dppmov<0x121>(v));
  return v;
}
__device__ inline float rowsum16(float v) {
  v += dppmov<0x128>(v);
  v += dppmov<0x124>(v);
  v += dppmov<0x122>(v);
  v += dppmov<0x121>(v);
  return v;
}

// ---------- fp32 -> bf16 conversion ----------

__global__ void cvt_multi(const float4* __restrict__ s0, const float4* __restrict__ s1,
                          const float4* __restrict__ s2, const float4* __restrict__ s3,
                          ushort4* __restrict__ d0, ushort4* __restrict__ d1,
                          ushort4* __restrict__ d2, ushort4* __restrict__ d3, int n4) {
  const float4* s; ushort4* d;
  switch (blockIdx.y) {
    case 0: s = s0; d = d0; break;
    case 1: s = s1; d = d1; break;
    case 2: s = s2; d = d2; break;
    default: s = s3; d = d3; break;
  }
  int stride = gridDim.x * blockDim.x;
  for (int i = blockIdx.x * blockDim.x + threadIdx.x; i < n4; i += stride) {
    float4 v = s[i];
    ushort4 o;
    o.x = f2bf(v.x); o.y = f2bf(v.y); o.z = f2bf(v.z); o.w = f2bf(v.w);
    d[i] = o;
  }
}

// ---------- per-(b, kv-tile) padding-mask OR flags ----------

__global__ void mask_flags(const unsigned char* __restrict__ mask,
                           unsigned char* __restrict__ flags) {
  int t = threadIdx.x;   // 0..127
  if (t >= 128) return;
  const uint4* p = (const uint4*)(mask + (size_t)t * 64);
  uint4 a = p[0], b = p[1], c = p[2], d = p[3];
  u32 v = a.x | a.y | a.z | a.w | b.x | b.y | b.z | b.w |
          c.x | c.y | c.z | c.w | d.x | d.y | d.z | d.w;
  flags[t] = v ? 1 : 0;
}

// ---------- 8-phase 256x256 QKV projection (T2+T3+T4+T5) ----------
// BK=64, 8 waves (2M x 4N), LDS 128KB: sA/sB[buf][half][128][64] bf16,
// XOR-swizzled (chunk ^= row&7 on source, byte ^ (row&7)<<4 on ds_read).
// Per K-tile slot: 4 phases = 4 C-quadrants x 16 MFMA; each phase stages one
// half-tile (2 gload_lds) whose previous-generation data died >=3 barriers ago:
//   s1: Bh1(t+1)->buf^1   s2: Ah1(t+1)->buf^1   s3: Bh0(t+2)->buf   s4: Ah0(t+2)->buf
// (B halves of a tile are last ds_read at its s2; A halves at its s3.)
// Per-phase gate: vmcnt(4) (2 half-tiles stay in flight) + s_barrier + sched_barrier.

#define GATE() do { \
    asm volatile("s_waitcnt vmcnt(4)" ::: "memory"); \
    __builtin_amdgcn_s_barrier(); \
    __builtin_amdgcn_sched_barrier(0); \
  } while (0)

#define READ_A(buf, qm)                                                        \
  do {                                                                         \
    const char* base_ = (const char*)&sA[buf][wm][0];                          \
    _Pragma("unroll")                                                          \
    for (int fi = 0; fi < 4; ++fi) {                                           \
      _Pragma("unroll")                                                        \
      for (int kk = 0; kk < 2; ++kk) {                                         \
        int row_ = (qm) * 64 + fi * 16 + r;                                    \
        int j_ = kk * 4 + g;                                                   \
        af[fi][kk] = *(const bf16x8*)(base_ + row_ * 128 +                     \
                                      ((j_ ^ (row_ & 7)) << 4));               \
      }                                                                        \
    }                                                                          \
  } while (0)

#define READ_B(buf, qn, BF)                                                    \
  do {                                                                         \
    const char* base_ = (const char*)&sB[buf][wn >> 1][0];                     \
    _Pragma("unroll")                                                          \
    for (int fj = 0; fj < 2; ++fj) {                                           \
      _Pragma("unroll")                                                        \
      for (int kk = 0; kk < 2; ++kk) {                                         \
        int row_ = (wn & 1) * 64 + (qn) * 32 + fj * 16 + r;                    \
        int j_ = kk * 4 + g;                                                   \
        BF[fj][kk] = *(const bf16x8*)(base_ + row_ * 128 +                     \
                                      ((j_ ^ (row_ & 7)) << 4));               \
      }                                                                        \
    }                                                                          \
  } while (0)

#define MFMA8(qm, qn, BF)                                                      \
  do {                                                                         \
    __builtin_amdgcn_s_setprio(1);                                             \
    _Pragma("unroll")                                                          \
    for (int kk = 0; kk < 2; ++kk) {                                           \
      _Pragma("unroll")                                                        \
      for (int fi = 0; fi < 4; ++fi) {                                         \
        _Pragma("unroll")                                                      \
        for (int fj = 0; fj < 2; ++fj) {                                       \
          acc[(qm) * 4 + fi][(qn) * 2 + fj] =                                  \
              __builtin_amdgcn_mfma_f32_16x16x32_bf16(                         \
                  af[fi][kk], BF[fj][kk], acc[(qm) * 4 + fi][(qn) * 2 + fj],   \
                  0, 0, 0);                                                    \
        }                                                                      \
      }                                                                        \
    }                                                                          \
    __builtin_amdgcn_s_setprio(0);                                             \
  } while (0)

__global__ __launch_bounds__(512) void gemm_qkv8(
    const u16* __restrict__ Aq, const u16* __restrict__ Ak, const u16* __restrict__ Av,
    const u16* __restrict__ Wqb, const u16* __restrict__ Wkb, const u16* __restrict__ Wvb,
    const float* __restrict__ bqp, const float* __restrict__ bkp, const float* __restrict__ bvp,
    u16* __restrict__ Qh, u16* __restrict__ Kh, u16* __restrict__ Vt,
    int M, int N, int K) {
  __shared__ u16 sA[2][2][128 * 64];   // 64 KB
  __shared__ u16 sB[2][2][128 * 64];   // 64 KB

  // XCD-chunked bijective swizzle (nwg = 4*32*3 = 384, %8==0)
  const int hw = blockIdx.z * 128 + blockIdx.y * 4 + blockIdx.x;
  const int lg = (hw & 7) * 48 + (hw >> 3);
  const int z = lg >> 7;           // /128
  const int rem = lg & 127;
  const int m0 = (rem >> 2) * 256;
  const int n0 = (rem & 3) * 256;

  const u16* A  = (z == 0) ? Aq : (z == 1) ? Ak : Av;
  const u16* Bt = (z == 0) ? Wqb : (z == 1) ? Wkb : Wvb;
  const float* bias = (z == 0) ? bqp : (z == 1) ? bkp : bvp;

  const int tid = threadIdx.x;
  const int lane = tid & 63;
  const int wave = tid >> 6;       // 0..7
  const int g = lane >> 4;
  const int r = lane & 15;
  const int wm = wave >> 2;        // 0..1  (128 rows each)
  const int wn = wave & 3;         // 0..3  (64 cols each)

  f32x4 acc[8][4] = {};
  bf16x8 af[4][2], bf0[2][2], bf1[2][2];

  auto stageA = [&](int buf, int half, int kt) {
    const int k0 = kt * 64;
#pragma unroll
    for (int i = 0; i < 2; ++i) {
      int c = tid + i * 512;
      int row = c >> 3, cc = c & 7;
      gload_lds16(A + (size_t)(m0 + half * 128 + row) * K + k0 + ((cc ^ (row & 7)) * 8),
                  &sA[buf][half][0] + c * 8);
    }
  };
  auto stageB = [&](int buf, int half, int kt) {
    const int k0 = kt * 64;
#pragma unroll
    for (int i = 0; i < 2; ++i) {
      int c = tid + i * 512;
      int row = c >> 3, cc = c & 7;
      gload_lds16(Bt + (size_t)(n0 + half * 128 + row) * K + k0 + ((cc ^ (row & 7)) * 8),
                  &sB[buf][half][0] + c * 8);
    }
  };

  const int NT = K / 64;   // 16

  // prologue: tile0 fully + tile1 {Bh0, Ah0}; drain; barrier
  stageB(0, 0, 0); stageB(0, 1, 0); stageA(0, 0, 0); stageA(0, 1, 0);
  stageB(1, 0, 1); stageA(1, 0, 1);
  asm volatile("s_waitcnt vmcnt(0)" ::: "memory");
  __builtin_amdgcn_s_barrier();
  __builtin_amdgcn_sched_barrier(0);

  for (int t = 0; t < NT; ++t) {
    const int buf = t & 1;
    // ---- s1: quadrant (0,0); stage Bh1(t+1) ----
    READ_A(buf, 0);
    READ_B(buf, 0, bf0);
    if (t + 1 < NT) stageB(buf ^ 1, 1, t + 1);
    GATE();
    MFMA8(0, 0, bf0);
    // ---- s2: quadrant (0,1); stage Ah1(t+1) ----
    READ_B(buf, 1, bf1);
    if (t + 1 < NT) stageA(buf ^ 1, 1, t + 1);
    GATE();
    MFMA8(0, 1, bf1);
    // ---- s3: quadrant (1,0); stage Bh0(t+2) ----
    READ_A(buf, 1);
    if (t + 2 < NT) stageB(buf, 0, t + 2);
    GATE();
    MFMA8(1, 0, bf0);
    // ---- s4: quadrant (1,1); stage Ah0(t+2) ----
    if (t + 2 < NT) stageA(buf, 0, t + 2);
    GATE();
    MFMA8(1, 1, bf1);
  }

  // epilogue: bias + head-layout stores
#pragma unroll
  for (int fi = 0; fi < 8; ++fi) {
    int rowb = m0 + wm * 128 + fi * 16 + g * 4;
#pragma unroll
    for (int fj = 0; fj < 4; ++fj) {
      int col = n0 + wn * 64 + fj * 16 + r;
      float bv = bias[col];
#pragma unroll
      for (int q = 0; q < 4; ++q) {
        int row = rowb + q;
        float v = acc[fi][fj][q] + bv;
        int b = row >> 10, t = row & 1023, h = col >> 6, d = col & 63;
        if (z == 0) {
          Qh[((((size_t)b * 16 + h) << 10) + t) * 64 + d] = f2bf(v * QSCALE);
        } else if (z == 1) {
          Kh[((((size_t)b * 16 + h) << 10) + t) * 64 + d] = f2bf(v);
        } else {
          Vt[(((size_t)b * 16 + h) * 64 + d) * 1024 + t] = f2bf(v);
        }
      }
    }
  }
}

// ---------- O-projection GEMM: r9 2-phase structure + XCD swizzle ----------

__global__ __launch_bounds__(256) void gemm_o(
    const u16* __restrict__ A, const u16* __restrict__ Bt,
    const float* __restrict__ bias, float* __restrict__ Cout,
    int M, int N, int K) {
  constexpr int BK = 32;
  __shared__ u16 sA[2][128 * BK];
  __shared__ u16 sB[2][128 * BK];

  const int hw = blockIdx.y * 8 + blockIdx.x;   // grid (8,64) = 512
  const int lg = (hw & 7) * 64 + (hw >> 3);
  const int m0 = (lg >> 3) * 128;
  const int n0 = (lg & 7) * 128;

  const int tid = threadIdx.x;
  const int lane = tid & 63;
  const int wave = tid >> 6;
  const int g = lane >> 4;
  const int r = lane & 15;
  const int wr = wave >> 1, wc = wave & 1;

  f32x4 acc[4][4] = {};

  auto stage = [&](int buf, int kt) {
    const int k0 = kt * BK;
#pragma unroll
    for (int i = 0; i < 2; ++i) {
      int c = tid + i * 256;
      int row = c >> 2, cc = c & 3;
      gload_lds16(A + (size_t)(m0 + row) * K + k0 + cc * 8, &sA[buf][0] + c * 8);
    }
#pragma unroll
    for (int i = 0; i < 2; ++i) {
      int c = tid + i * 256;
      int row = c >> 2, cc = c & 3;
      gload_lds16(Bt + (size_t)(n0 + row) * K + k0 + cc * 8, &sB[buf][0] + c * 8);
    }
  };

  stage(0, 0);
  const int NT = K / BK;
  for (int kt = 0; kt < NT; ++kt) {
    __syncthreads();
    if (kt + 1 < NT) stage((kt + 1) & 1, kt + 1);
    const u16* a_base = &sA[kt & 1][0];
    const u16* b_base = &sB[kt & 1][0];
    bf16x8 avf[4], bvf[4];
#pragma unroll
    for (int i = 0; i < 4; ++i) {
      avf[i] = *(const bf16x8*)(a_base + (wr * 64 + i * 16 + r) * BK + g * 8);
      bvf[i] = *(const bf16x8*)(b_base + (wc * 64 + i * 16 + r) * BK + g * 8);
    }
#pragma unroll
    for (int i = 0; i < 4; ++i)
#pragma unroll
      for (int j = 0; j < 4; ++j)
        acc[i][j] = __builtin_amdgcn_mfma_f32_16x16x32_bf16(avf[i], bvf[j], acc[i][j], 0, 0, 0);
  }

#pragma unroll
  for (int i = 0; i < 4; ++i) {
    int rowb = m0 + wr * 64 + i * 16 + g * 4;
#pragma unroll
    for (int j = 0; j < 4; ++j) {
      int col = n0 + wc * 64 + j * 16 + r;
      float bv = bias[col];
#pragma unroll
      for (int q = 0; q < 4; ++q) {
        int row = rowb + q;
        Cout[(size_t)row * N + col] = acc[i][j][q] + bv;
      }
    }
  }
}

// ---------- flash attention (r9: defer-max + setprio) ----------

__global__ __launch_bounds__(256) void attn_fwd(
    const u16* __restrict__ Qh, const u16* __restrict__ Kh,
    const u16* __restrict__ Vt, const unsigned char* __restrict__ mask,
    const unsigned char* __restrict__ padflags,
    u16* __restrict__ O) {
  constexpr int S = 1024, DH = 64;
  __shared__ u16 sK[2][64 * 64];
  __shared__ u16 sV[2][64 * 64];
  __shared__ u16 sP[4][16 * 64];

  const int tid = threadIdx.x, lane = tid & 63, wave = tid >> 6;
  const int g = lane >> 4, r = lane & 15;
  const int bh = blockIdx.x;
  const int qt = (int)gridDim.y - 1 - (int)blockIdx.y;
  const int b = bh >> 4, h = bh & 15;
  const int qw = qt * 128 + wave * 32;

  bf16x8 qf[2][2];
#pragma unroll
  for (int u = 0; u < 2; ++u) {
    const u16* Qb = Qh + ((size_t)bh * S + qw + u * 16 + r) * DH;
    qf[u][0] = *(const bf16x8*)(Qb + g * 8);
    qf[u][1] = *(const bf16x8*)(Qb + 32 + g * 8);
  }

  f32x4 acc[2][4] = {};
  float mrun[2][4], lrun[2][4];
#pragma unroll
  for (int u = 0; u < 2; ++u)
#pragma unroll
    for (int i = 0; i < 4; ++i) { mrun[u][i] = -INFINITY; lrun[u][i] = 0.f; }

  auto stage = [&](int buf, int kvt) {
    const int s0k = kvt * 64;
#pragma unroll
    for (int i = 0; i < 2; ++i) {
      int c = tid + i * 256;
      int row = c >> 3;
      int cc = (c & 7) ^ (row & 7);
      gload_lds16(Kh + ((size_t)bh * S + s0k + row) * DH + cc * 8, &sK[buf][0] + c * 8);
      gload_lds16(Vt + ((size_t)bh * DH + row) * S + s0k + cc * 8, &sV[buf][0] + c * 8);
    }
  };

  const int NT = 2 * (qt + 1);
  stage(0, 0);
  for (int kvt = 0; kvt < NT; ++kvt) {
    __syncthreads();
    if (kvt + 1 < NT) stage((kvt + 1) & 1, kvt + 1);
    const int cur = kvt & 1;
    const int s0 = kvt * 64;
    const bool pad = padflags[b * 16 + (s0 >> 6)] != 0;
    const u16* Kb = &sK[cur][0];
    const u16* Vb = &sV[cur][0];
    u16* Pw = &sP[wave][0];

#pragma unroll
    for (int u = 0; u < 2; ++u) {
      const int qg = qw + u * 16;
      if (s0 > qg + 15) continue;
      const bool diag = (s0 + 63 > qg);

      f32x4 sc[4] = {};
      __builtin_amdgcn_s_setprio(1);
#pragma unroll
      for (int ss = 0; ss < 4; ++ss) {
#pragma unroll
        for (int kc = 0; kc < 2; ++kc) {
          int krow = ss * 16 + r;
          int byteoff = krow * 128 + kc * 64 + g * 16;
          bf16x8 kf = *(const bf16x8*)((const char*)Kb + (byteoff ^ ((krow & 7) << 4)));
          sc[ss] = __builtin_amdgcn_mfma_f32_16x16x32_bf16(qf[u][kc], kf, sc[ss], 0, 0, 0);
        }
      }
      __builtin_amdgcn_s_setprio(0);

      float sv[4][4];
      float pmax[4] = {-INFINITY, -INFINITY, -INFINITY, -INFINITY};
#pragma unroll
      for (int ss = 0; ss < 4; ++ss) {
        float padd = 0.f;
        if (pad) {
          int s_g = s0 + ss * 16 + r;
          if (mask[(size_t)b * S + s_g]) padd = -INFINITY;
        }
#pragma unroll
        for (int reg = 0; reg < 4; ++reg) {
          float v = sc[ss][reg] + padd;
          if (diag) {
            int s_g = s0 + ss * 16 + r;
            int q_g = qg + g * 4 + reg;
            if (s_g > q_g) v = -INFINITY;
          }
          sv[ss][reg] = v;
          pmax[reg] = fmaxf(pmax[reg], v);
        }
      }

      float tm[4];
#pragma unroll
      for (int reg = 0; reg < 4; ++reg) tm[reg] = rowmax16(pmax[reg]);
      float dmax = fmaxf(fmaxf(tm[0] - mrun[u][0], tm[1] - mrun[u][1]),
                         fmaxf(tm[2] - mrun[u][2], tm[3] - mrun[u][3]));
      if (__any(dmax > DEFER_THR)) {
#pragma unroll
        for (int reg = 0; reg < 4; ++reg) {
          float newm = fmaxf(mrun[u][reg], tm[reg]);
          float alpha = (newm == -INFINITY) ? 1.f : exp2f(mrun[u][reg] - newm);
          mrun[u][reg] = newm;
          float rs = 0.f;
#pragma unroll
          for (int ss = 0; ss < 4; ++ss) {
            float p = (newm == -INFINITY) ? 0.f : exp2f(sv[ss][reg] - newm);
            sv[ss][reg] = p;
            rs += p;
          }
          rs = rowsum16(rs);
          lrun[u][reg] = lrun[u][reg] * alpha + rs;
#pragma unroll
          for (int df = 0; df < 4; ++df) acc[u][df][reg] *= alpha;
        }
      } else {
#pragma unroll
        for (int reg = 0; reg < 4; ++reg) {
          float m = mrun[u][reg];
          float rs = 0.f;
#pragma unroll
          for (int ss = 0; ss < 4; ++ss) {
            float p = (m == -INFINITY) ? 0.f : exp2f(sv[ss][reg] - m);
            sv[ss][reg] = p;
            rs += p;
          }
          rs = rowsum16(rs);
          lrun[u][reg] += rs;
        }
      }

#pragma unroll
      for (int ss = 0; ss < 4; ++ss) {
#pragma unroll
        for (int reg = 0; reg < 4; ++reg) {
          int qrow = g * 4 + reg;
          int byteoff = qrow * 128 + (ss * 16 + r) * 2;
          u32 bits = __builtin_bit_cast(u32, sv[ss][reg]);
          *(u16*)((char*)Pw + (byteoff ^ ((qrow & 7) << 4))) = (u16)(bits >> 16);
        }
      }

      __builtin_amdgcn_s_setprio(1);
#pragma unroll
      for (int sc2 = 0; sc2 < 2; ++sc2) {
        int pbyte = r * 128 + sc2 * 64 + g * 16;
        bf16x8 pf = *(const bf16x8*)((const char*)Pw + (pbyte ^ ((r & 7) << 4)));
#pragma unroll
        for (int df = 0; df < 4; ++df) {
          int vrow = df * 16 + r;
          int vbyte = vrow * 128 + sc2 * 64 + g * 16;
          bf16x8 vf = *(const bf16x8*)((const char*)Vb + (vbyte ^ ((vrow & 7) << 4)));
          acc[u][df] = __builtin_amdgcn_mfma_f32_16x16x32_bf16(pf, vf, acc[u][df], 0, 0, 0);
        }
      }
      __builtin_amdgcn_s_setprio(0);
    }
  }

#pragma unroll
  for (int u = 0; u < 2; ++u) {
#pragma unroll
    for (int reg = 0; reg < 4; ++reg) {
      float l = lrun[u][reg];
      float inv = (l > 0.f) ? 1.f / l : 0.f;
      int t = qw + u * 16 + g * 4 + reg;
#pragma unroll
      for (int df = 0; df < 4; ++df) {
        float vo = acc[u][df][reg] * inv;
        O[((size_t)b * 1024 + t) * 1024 + h * 64 + df * 16 + r] = f2bf(vo);
      }
    }
  }
}

// ---------- launch ----------

extern "C" void kernel_launch(void* const* d_in, const int* in_sizes, int n_in,
                              void* d_out, int out_size, void* d_ws, size_t ws_size,
                              hipStream_t stream) {
  const float* q  = (const float*)d_in[0];
  const float* k  = (const float*)d_in[1];
  const float* v  = (const float*)d_in[2];
  const unsigned char* mask = (const unsigned char*)d_in[3];
  const float* Wq = (const float*)d_in[4];
  const float* bq = (const float*)d_in[5];
  const float* Wk = (const float*)d_in[6];
  const float* bk = (const float*)d_in[7];
  const float* Wv = (const float*)d_in[8];
  const float* bv = (const float*)d_in[9];
  const float* Wo = (const float*)d_in[10];
  const float* bo = (const float*)d_in[11];

  const int M = 8192, N = 1024, K = 1024;
  const size_t MB = 1u << 20;
  char* ws = (char*)d_ws;

  u16* Aq   = (u16*)(ws);                 // 16MB, reused as AttO after QKV GEMM
  u16* Ak   = (u16*)(ws + 16 * MB);
  u16* Av   = (u16*)(ws + 32 * MB);
  u16* Qh   = (u16*)(ws + 48 * MB);
  u16* Kh   = (u16*)(ws + 64 * MB);
  u16* Vt   = (u16*)(ws + 80 * MB);
  u16* Wqb  = (u16*)(ws + 96 * MB);
  u16* Wkb  = Wqb + (1u << 20);
  u16* Wvb  = Wkb + (1u << 20);
  u16* Wob  = Wvb + (1u << 20);
  unsigned char* flags = (unsigned char*)(ws + 104 * MB);
  u16* AttO = Aq;

  cvt_multi<<<dim3(1024, 3), 256, 0, stream>>>(
      (const float4*)q, (const float4*)k, (const float4*)v, (const float4*)q,
      (ushort4*)Aq, (ushort4*)Ak, (ushort4*)Av, (ushort4*)Aq, (M * K) / 4);
  cvt_multi<<<dim3(256, 4), 256, 0, stream>>>(
      (const float4*)Wq, (const float4*)Wk, (const float4*)Wv, (const float4*)Wo,
      (ushort4*)Wqb, (ushort4*)Wkb, (ushort4*)Wvb, (ushort4*)Wob, (N * K) / 4);
  mask_flags<<<1, 128, 0, stream>>>(mask, flags);

  gemm_qkv8<<<dim3(4, 32, 3), 512, 0, stream>>>(
      Aq, Ak, Av, Wqb, Wkb, Wvb, bq, bk, bv, Qh, Kh, Vt, M, N, K);

  attn_fwd<<<dim3(128, 8), 256, 0, stream>>>(Qh, Kh, Vt, mask, flags, AttO);

  gemm_o<<<dim3(8, 64), 256, 0, stream>>>(
      AttO, Wob, bo, (float*)d_out, M, N, K);
}

// Round 11
// 230.046 us; speedup vs baseline: 1.0500x; 1.0500x over previous
//
#include <hip/hip_runtime.h>
#include <hip/hip_bf16.h>

typedef unsigned short u16;
typedef unsigned int u32;
typedef __attribute__((ext_vector_type(8))) short bf16x8;
typedef __attribute__((ext_vector_type(4))) float f32x4;

#define LOG2E 1.44269504088896340736f
#define QSCALE (0.125f * LOG2E)
#define DEFER_THR 8.0f

#define WAITCNT_VM(N) asm volatile("s_waitcnt vmcnt(" #N ")" ::: "memory")

// ---------- helpers ----------

__device__ inline u16 f2bf(float f) {            // RNE
  union { float f; u32 u; } v; v.f = f;
  u32 r = v.u + 0x7fffu + ((v.u >> 16) & 1u);
  return (u16)(r >> 16);
}

__device__ inline void gload_lds16(const void* g, void* l) {
  __builtin_amdgcn_global_load_lds(
      (const __attribute__((address_space(1))) u32*)g,
      (__attribute__((address_space(3))) u32*)l, 16, 0, 0);
}

// DPP move within 16-lane rows (row_ror:N = 0x120+N)
template<int CTRL>
__device__ inline float dppmov(float x) {
  int i = __builtin_bit_cast(int, x);
  int r = __builtin_amdgcn_update_dpp(i, i, CTRL, 0xf, 0xf, false);
  return __builtin_bit_cast(float, r);
}
__device__ inline float rowmax16(float v) {
  v = fmaxf(v, dppmov<0x128>(v));
  v = fmaxf(v, dppmov<0x124>(v));
  v = fmaxf(v, dppmov<0x122>(v));
  v = fmaxf(v, dppmov<0x121>(v));
  return v;
}
__device__ inline float rowsum16(float v) {
  v += dppmov<0x128>(v);
  v += dppmov<0x124>(v);
  v += dppmov<0x122>(v);
  v += dppmov<0x121>(v);
  return v;
}

// ---------- fp32 -> bf16 conversion ----------

__global__ void cvt_multi(const float4* __restrict__ s0, const float4* __restrict__ s1,
                          const float4* __restrict__ s2, const float4* __restrict__ s3,
                          ushort4* __restrict__ d0, ushort4* __restrict__ d1,
                          ushort4* __restrict__ d2, ushort4* __restrict__ d3, int n4) {
  const float4* s; ushort4* d;
  switch (blockIdx.y) {
    case 0: s = s0; d = d0; break;
    case 1: s = s1; d = d1; break;
    case 2: s = s2; d = d2; break;
    default: s = s3; d = d3; break;
  }
  int stride = gridDim.x * blockDim.x;
  for (int i = blockIdx.x * blockDim.x + threadIdx.x; i < n4; i += stride) {
    float4 v = s[i];
    ushort4 o;
    o.x = f2bf(v.x); o.y = f2bf(v.y); o.z = f2bf(v.z); o.w = f2bf(v.w);
    d[i] = o;
  }
}

// ---------- per-(b, kv-tile) padding-mask OR flags ----------

__global__ void mask_flags(const unsigned char* __restrict__ mask,
                           unsigned char* __restrict__ flags) {
  int t = threadIdx.x;   // 0..127
  if (t >= 128) return;
  const uint4* p = (const uint4*)(mask + (size_t)t * 64);
  uint4 a = p[0], b = p[1], c = p[2], d = p[3];
  u32 v = a.x | a.y | a.z | a.w | b.x | b.y | b.z | b.w |
          c.x | c.y | c.z | c.w | d.x | d.y | d.z | d.w;
  flags[t] = v ? 1 : 0;
}

// ---------- fused Q/K/V projection: r3/r9 2-phase structure + T4 graft ----------
// ONLY change vs r9: 2-buffer drain-to-0 -> 3-buffer counted vmcnt(4).
// Per iteration: gate{vmcnt(4); s_barrier; sched_barrier} -> stage(t+2) ->
// compute(t). Tile t+2's DMA stays in flight across 2 barriers; never drain
// to 0 mid-loop. Hazards: stage(t+2) overwrites buf[(t-1)%3] whose readers
// finished before the barrier just crossed; every wave vmcnt(4)s tile t before
// the barrier. LDS 48KB -> 3 blocks/CU. XCD-chunked bijective swizzle kept.

__global__ __launch_bounds__(256) void gemm_qkv(
    const u16* __restrict__ Aq, const u16* __restrict__ Ak, const u16* __restrict__ Av,
    const u16* __restrict__ Wqb, const u16* __restrict__ Wkb, const u16* __restrict__ Wvb,
    const float* __restrict__ bqp, const float* __restrict__ bkp, const float* __restrict__ bvp,
    u16* __restrict__ Qh, u16* __restrict__ Kh, u16* __restrict__ Vt,
    int M, int N, int K) {
  constexpr int BK = 32;
  __shared__ u16 sA[3][128 * BK];
  __shared__ u16 sB[3][128 * BK];

  // XCD-chunked bijective swizzle (nwg = 1536, %8==0)
  const int hw = blockIdx.z * 512 + blockIdx.y * 8 + blockIdx.x;
  const int lg = (hw & 7) * 192 + (hw >> 3);
  const int z = lg / 512;
  const int rem = lg - z * 512;
  const int m0 = (rem >> 3) * 128;
  const int n0 = (rem & 7) * 128;

  const u16* A  = (z == 0) ? Aq : (z == 1) ? Ak : Av;
  const u16* Bt = (z == 0) ? Wqb : (z == 1) ? Wkb : Wvb;
  const float* bias = (z == 0) ? bqp : (z == 1) ? bkp : bvp;

  const int tid = threadIdx.x;
  const int lane = tid & 63;
  const int wave = tid >> 6;
  const int g = lane >> 4;
  const int r = lane & 15;
  const int wr = wave >> 1, wc = wave & 1;

  f32x4 acc[4][4] = {};

  auto stage = [&](int buf, int kt) {   // exactly 4 gload_lds per thread
    const int k0 = kt * BK;
#pragma unroll
    for (int i = 0; i < 2; ++i) {
      int c = tid + i * 256;
      int row = c >> 2, cc = c & 3;
      gload_lds16(A + (size_t)(m0 + row) * K + k0 + cc * 8, &sA[buf][0] + c * 8);
    }
#pragma unroll
    for (int i = 0; i < 2; ++i) {
      int c = tid + i * 256;
      int row = c >> 2, cc = c & 3;
      gload_lds16(Bt + (size_t)(n0 + row) * K + k0 + cc * 8, &sB[buf][0] + c * 8);
    }
  };

  auto compute = [&](int buf) {
    const u16* a_base = &sA[buf][0];
    const u16* b_base = &sB[buf][0];
    bf16x8 avf[4], bvf[4];
#pragma unroll
    for (int i = 0; i < 4; ++i) {
      avf[i] = *(const bf16x8*)(a_base + (wr * 64 + i * 16 + r) * BK + g * 8);
      bvf[i] = *(const bf16x8*)(b_base + (wc * 64 + i * 16 + r) * BK + g * 8);
    }
#pragma unroll
    for (int i = 0; i < 4; ++i)
#pragma unroll
      for (int j = 0; j < 4; ++j)
        acc[i][j] = __builtin_amdgcn_mfma_f32_16x16x32_bf16(avf[i], bvf[j], acc[i][j], 0, 0, 0);
  };

  const int NT = K / BK;   // 32

  stage(0, 0);
  stage(1, 1);             // 8 loads outstanding

  int cur = 0;             // buffer holding tile kt
  for (int kt = 0; kt < NT; ++kt) {
    if (kt + 1 < NT) { WAITCNT_VM(4); } else { WAITCNT_VM(0); }
    __builtin_amdgcn_s_barrier();
    __builtin_amdgcn_sched_barrier(0);
    if (kt + 2 < NT) {
      int s2 = cur + 2; if (s2 >= 3) s2 -= 3;
      stage(s2, kt + 2);
    }
    compute(cur);
    cur = (cur == 2) ? 0 : cur + 1;
  }

#pragma unroll
  for (int i = 0; i < 4; ++i) {
    int rowb = m0 + wr * 64 + i * 16 + g * 4;
#pragma unroll
    for (int j = 0; j < 4; ++j) {
      int col = n0 + wc * 64 + j * 16 + r;
      float bv = bias[col];
#pragma unroll
      for (int q = 0; q < 4; ++q) {
        int row = rowb + q;
        float v = acc[i][j][q] + bv;
        int b = row >> 10, t = row & 1023, h = col >> 6, d = col & 63;
        if (z == 0) {
          Qh[((((size_t)b * 16 + h) << 10) + t) * 64 + d] = f2bf(v * QSCALE);
        } else if (z == 1) {
          Kh[((((size_t)b * 16 + h) << 10) + t) * 64 + d] = f2bf(v);
        } else {
          Vt[(((size_t)b * 16 + h) * 64 + d) * 1024 + t] = f2bf(v);
        }
      }
    }
  }
}

// ---------- O-projection GEMM: r9 2-phase structure + XCD swizzle (frozen) ----------

__global__ __launch_bounds__(256) void gemm_o(
    const u16* __restrict__ A, const u16* __restrict__ Bt,
    const float* __restrict__ bias, float* __restrict__ Cout,
    int M, int N, int K) {
  constexpr int BK = 32;
  __shared__ u16 sA[2][128 * BK];
  __shared__ u16 sB[2][128 * BK];

  const int hw = blockIdx.y * 8 + blockIdx.x;   // grid (8,64) = 512
  const int lg = (hw & 7) * 64 + (hw >> 3);
  const int m0 = (lg >> 3) * 128;
  const int n0 = (lg & 7) * 128;

  const int tid = threadIdx.x;
  const int lane = tid & 63;
  const int wave = tid >> 6;
  const int g = lane >> 4;
  const int r = lane & 15;
  const int wr = wave >> 1, wc = wave & 1;

  f32x4 acc[4][4] = {};

  auto stage = [&](int buf, int kt) {
    const int k0 = kt * BK;
#pragma unroll
    for (int i = 0; i < 2; ++i) {
      int c = tid + i * 256;
      int row = c >> 2, cc = c & 3;
      gload_lds16(A + (size_t)(m0 + row) * K + k0 + cc * 8, &sA[buf][0] + c * 8);
    }
#pragma unroll
    for (int i = 0; i < 2; ++i) {
      int c = tid + i * 256;
      int row = c >> 2, cc = c & 3;
      gload_lds16(Bt + (size_t)(n0 + row) * K + k0 + cc * 8, &sB[buf][0] + c * 8);
    }
  };

  stage(0, 0);
  const int NT = K / BK;
  for (int kt = 0; kt < NT; ++kt) {
    __syncthreads();
    if (kt + 1 < NT) stage((kt + 1) & 1, kt + 1);
    const u16* a_base = &sA[kt & 1][0];
    const u16* b_base = &sB[kt & 1][0];
    bf16x8 avf[4], bvf[4];
#pragma unroll
    for (int i = 0; i < 4; ++i) {
      avf[i] = *(const bf16x8*)(a_base + (wr * 64 + i * 16 + r) * BK + g * 8);
      bvf[i] = *(const bf16x8*)(b_base + (wc * 64 + i * 16 + r) * BK + g * 8);
    }
#pragma unroll
    for (int i = 0; i < 4; ++i)
#pragma unroll
      for (int j = 0; j < 4; ++j)
        acc[i][j] = __builtin_amdgcn_mfma_f32_16x16x32_bf16(avf[i], bvf[j], acc[i][j], 0, 0, 0);
  }

#pragma unroll
  for (int i = 0; i < 4; ++i) {
    int rowb = m0 + wr * 64 + i * 16 + g * 4;
#pragma unroll
    for (int j = 0; j < 4; ++j) {
      int col = n0 + wc * 64 + j * 16 + r;
      float bv = bias[col];
#pragma unroll
      for (int q = 0; q < 4; ++q) {
        int row = rowb + q;
        Cout[(size_t)row * N + col] = acc[i][j][q] + bv;
      }
    }
  }
}

// ---------- flash attention (r9: defer-max + setprio, frozen) ----------

__global__ __launch_bounds__(256) void attn_fwd(
    const u16* __restrict__ Qh, const u16* __restrict__ Kh,
    const u16* __restrict__ Vt, const unsigned char* __restrict__ mask,
    const unsigned char* __restrict__ padflags,
    u16* __restrict__ O) {
  constexpr int S = 1024, DH = 64;
  __shared__ u16 sK[2][64 * 64];
  __shared__ u16 sV[2][64 * 64];
  __shared__ u16 sP[4][16 * 64];

  const int tid = threadIdx.x, lane = tid & 63, wave = tid >> 6;
  const int g = lane >> 4, r = lane & 15;
  const int bh = blockIdx.x;
  const int qt = (int)gridDim.y - 1 - (int)blockIdx.y;
  const int b = bh >> 4, h = bh & 15;
  const int qw = qt * 128 + wave * 32;

  bf16x8 qf[2][2];
#pragma unroll
  for (int u = 0; u < 2; ++u) {
    const u16* Qb = Qh + ((size_t)bh * S + qw + u * 16 + r) * DH;
    qf[u][0] = *(const bf16x8*)(Qb + g * 8);
    qf[u][1] = *(const bf16x8*)(Qb + 32 + g * 8);
  }

  f32x4 acc[2][4] = {};
  float mrun[2][4], lrun[2][4];
#pragma unroll
  for (int u = 0; u < 2; ++u)
#pragma unroll
    for (int i = 0; i < 4; ++i) { mrun[u][i] = -INFINITY; lrun[u][i] = 0.f; }

  auto stage = [&](int buf, int kvt) {
    const int s0k = kvt * 64;
#pragma unroll
    for (int i = 0; i < 2; ++i) {
      int c = tid + i * 256;
      int row = c >> 3;
      int cc = (c & 7) ^ (row & 7);
      gload_lds16(Kh + ((size_t)bh * S + s0k + row) * DH + cc * 8, &sK[buf][0] + c * 8);
      gload_lds16(Vt + ((size_t)bh * DH + row) * S + s0k + cc * 8, &sV[buf][0] + c * 8);
    }
  };

  const int NT = 2 * (qt + 1);
  stage(0, 0);
  for (int kvt = 0; kvt < NT; ++kvt) {
    __syncthreads();
    if (kvt + 1 < NT) stage((kvt + 1) & 1, kvt + 1);
    const int cur = kvt & 1;
    const int s0 = kvt * 64;
    const bool pad = padflags[b * 16 + (s0 >> 6)] != 0;
    const u16* Kb = &sK[cur][0];
    const u16* Vb = &sV[cur][0];
    u16* Pw = &sP[wave][0];

#pragma unroll
    for (int u = 0; u < 2; ++u) {
      const int qg = qw + u * 16;
      if (s0 > qg + 15) continue;
      const bool diag = (s0 + 63 > qg);

      f32x4 sc[4] = {};
      __builtin_amdgcn_s_setprio(1);
#pragma unroll
      for (int ss = 0; ss < 4; ++ss) {
#pragma unroll
        for (int kc = 0; kc < 2; ++kc) {
          int krow = ss * 16 + r;
          int byteoff = krow * 128 + kc * 64 + g * 16;
          bf16x8 kf = *(const bf16x8*)((const char*)Kb + (byteoff ^ ((krow & 7) << 4)));
          sc[ss] = __builtin_amdgcn_mfma_f32_16x16x32_bf16(qf[u][kc], kf, sc[ss], 0, 0, 0);
        }
      }
      __builtin_amdgcn_s_setprio(0);

      float sv[4][4];
      float pmax[4] = {-INFINITY, -INFINITY, -INFINITY, -INFINITY};
#pragma unroll
      for (int ss = 0; ss < 4; ++ss) {
        float padd = 0.f;
        if (pad) {
          int s_g = s0 + ss * 16 + r;
          if (mask[(size_t)b * S + s_g]) padd = -INFINITY;
        }
#pragma unroll
        for (int reg = 0; reg < 4; ++reg) {
          float v = sc[ss][reg] + padd;
          if (diag) {
            int s_g = s0 + ss * 16 + r;
            int q_g = qg + g * 4 + reg;
            if (s_g > q_g) v = -INFINITY;
          }
          sv[ss][reg] = v;
          pmax[reg] = fmaxf(pmax[reg], v);
        }
      }

      float tm[4];
#pragma unroll
      for (int reg = 0; reg < 4; ++reg) tm[reg] = rowmax16(pmax[reg]);
      float dmax = fmaxf(fmaxf(tm[0] - mrun[u][0], tm[1] - mrun[u][1]),
                         fmaxf(tm[2] - mrun[u][2], tm[3] - mrun[u][3]));
      if (__any(dmax > DEFER_THR)) {
#pragma unroll
        for (int reg = 0; reg < 4; ++reg) {
          float newm = fmaxf(mrun[u][reg], tm[reg]);
          float alpha = (newm == -INFINITY) ? 1.f : exp2f(mrun[u][reg] - newm);
          mrun[u][reg] = newm;
          float rs = 0.f;
#pragma unroll
          for (int ss = 0; ss < 4; ++ss) {
            float p = (newm == -INFINITY) ? 0.f : exp2f(sv[ss][reg] - newm);
            sv[ss][reg] = p;
            rs += p;
          }
          rs = rowsum16(rs);
          lrun[u][reg] = lrun[u][reg] * alpha + rs;
#pragma unroll
          for (int df = 0; df < 4; ++df) acc[u][df][reg] *= alpha;
        }
      } else {
#pragma unroll
        for (int reg = 0; reg < 4; ++reg) {
          float m = mrun[u][reg];
          float rs = 0.f;
#pragma unroll
          for (int ss = 0; ss < 4; ++ss) {
            float p = (m == -INFINITY) ? 0.f : exp2f(sv[ss][reg] - m);
            sv[ss][reg] = p;
            rs += p;
          }
          rs = rowsum16(rs);
          lrun[u][reg] += rs;
        }
      }

#pragma unroll
      for (int ss = 0; ss < 4; ++ss) {
#pragma unroll
        for (int reg = 0; reg < 4; ++reg) {
          int qrow = g * 4 + reg;
          int byteoff = qrow * 128 + (ss * 16 + r) * 2;
          u32 bits = __builtin_bit_cast(u32, sv[ss][reg]);
          *(u16*)((char*)Pw + (byteoff ^ ((qrow & 7) << 4))) = (u16)(bits >> 16);
        }
      }

      __builtin_amdgcn_s_setprio(1);
#pragma unroll
      for (int sc2 = 0; sc2 < 2; ++sc2) {
        int pbyte = r * 128 + sc2 * 64 + g * 16;
        bf16x8 pf = *(const bf16x8*)((const char*)Pw + (pbyte ^ ((r & 7) << 4)));
#pragma unroll
        for (int df = 0; df < 4; ++df) {
          int vrow = df * 16 + r;
          int vbyte = vrow * 128 + sc2 * 64 + g * 16;
          bf16x8 vf = *(const bf16x8*)((const char*)Vb + (vbyte ^ ((vrow & 7) << 4)));
          acc[u][df] = __builtin_amdgcn_mfma_f32_16x16x32_bf16(pf, vf, acc[u][df], 0, 0, 0);
        }
      }
      __builtin_amdgcn_s_setprio(0);
    }
  }

#pragma unroll
  for (int u = 0; u < 2; ++u) {
#pragma unroll
    for (int reg = 0; reg < 4; ++reg) {
      float l = lrun[u][reg];
      float inv = (l > 0.f) ? 1.f / l : 0.f;
      int t = qw + u * 16 + g * 4 + reg;
#pragma unroll
      for (int df = 0; df < 4; ++df) {
        float vo = acc[u][df][reg] * inv;
        O[((size_t)b * 1024 + t) * 1024 + h * 64 + df * 16 + r] = f2bf(vo);
      }
    }
  }
}

// ---------- launch ----------

extern "C" void kernel_launch(void* const* d_in, const int* in_sizes, int n_in,
                              void* d_out, int out_size, void* d_ws, size_t ws_size,
                              hipStream_t stream) {
  const float* q  = (const float*)d_in[0];
  const float* k  = (const float*)d_in[1];
  const float* v  = (const float*)d_in[2];
  const unsigned char* mask = (const unsigned char*)d_in[3];
  const float* Wq = (const float*)d_in[4];
  const float* bq = (const float*)d_in[5];
  const float* Wk = (const float*)d_in[6];
  const float* bk = (const float*)d_in[7];
  const float* Wv = (const float*)d_in[8];
  const float* bv = (const float*)d_in[9];
  const float* Wo = (const float*)d_in[10];
  const float* bo = (const float*)d_in[11];

  const int M = 8192, N = 1024, K = 1024;
  const size_t MB = 1u << 20;
  char* ws = (char*)d_ws;

  u16* Aq   = (u16*)(ws);                 // 16MB, reused as AttO after QKV GEMM
  u16* Ak   = (u16*)(ws + 16 * MB);
  u16* Av   = (u16*)(ws + 32 * MB);
  u16* Qh   = (u16*)(ws + 48 * MB);
  u16* Kh   = (u16*)(ws + 64 * MB);
  u16* Vt   = (u16*)(ws + 80 * MB);
  u16* Wqb  = (u16*)(ws + 96 * MB);
  u16* Wkb  = Wqb + (1u << 20);
  u16* Wvb  = Wkb + (1u << 20);
  u16* Wob  = Wvb + (1u << 20);
  unsigned char* flags = (unsigned char*)(ws + 104 * MB);
  u16* AttO = Aq;

  cvt_multi<<<dim3(1024, 3), 256, 0, stream>>>(
      (const float4*)q, (const float4*)k, (const float4*)v, (const float4*)q,
      (ushort4*)Aq, (ushort4*)Ak, (ushort4*)Av, (ushort4*)Aq, (M * K) / 4);
  cvt_multi<<<dim3(256, 4), 256, 0, stream>>>(
      (const float4*)Wq, (const float4*)Wk, (const float4*)Wv, (const float4*)Wo,
      (ushort4*)Wqb, (ushort4*)Wkb, (ushort4*)Wvb, (ushort4*)Wob, (N * K) / 4);
  mask_flags<<<1, 128, 0, stream>>>(mask, flags);

  gemm_qkv<<<dim3(8, 64, 3), 256, 0, stream>>>(
      Aq, Ak, Av, Wqb, Wkb, Wvb, bq, bk, bv, Qh, Kh, Vt, M, N, K);

  attn_fwd<<<dim3(128, 8), 256, 0, stream>>>(Qh, Kh, Vt, mask, flags, AttO);

  gemm_o<<<dim3(8, 64), 256, 0, stream>>>(
      AttO, Wob, bo, (float*)d_out, M, N, K);
}